// Round 2
// baseline (2059.974 us; speedup 1.0000x reference)
//
#include <hip/hip_runtime.h>
#include <math.h>

#define NLEV 8

struct Scales { float s[NLEV]; };

// One thread per (point, task). task 0..7: static 3D level l (8 gathers,
// float4 out). task 8..31: dynamic (plane, level) pair (2 time slices x 4
// corners = 8 gathers, 1 float out, Lagrange basis folded in).
// task is the fastest-varying index -> coalesced stores; x reads are
// same-address broadcasts within the 32-lane group.
__global__ __launch_bounds__(256) void hg4d_split_kernel(
    const float* __restrict__ x,
    const float* __restrict__ tptr,
    const float* __restrict__ tstat,
    const float* __restrict__ txy,
    const float* __restrict__ txz,
    const float* __restrict__ tyz,
    float* __restrict__ outs,
    float* __restrict__ outd,
    int N, Scales sc)
{
    unsigned tid = blockIdx.x * blockDim.x + threadIdx.x;
    unsigned n = tid >> 5;
    unsigned task = tid & 31u;
    if (n >= (unsigned)N) return;

    float x0 = x[3 * (size_t)n + 0];
    float x1 = x[3 * (size_t)n + 1];
    float x2 = x[3 * (size_t)n + 2];

    if (task < 8u) {
        // ---- static 3D hash grid, one level ----
        const unsigned l = task;
        float s = sc.s[l];
        float p0 = x0 * s + 0.5f, p1 = x1 * s + 0.5f, p2 = x2 * s + 0.5f;
        float q0 = floorf(p0), q1 = floorf(p1), q2 = floorf(p2);
        float f0 = p0 - q0, f1 = p1 - q1, f2 = p2 - q2;
        unsigned u0 = (unsigned)q0, u1 = (unsigned)q1, u2 = (unsigned)q2;
        float g0 = 1.f - f0, g1 = 1.f - f1, g2 = 1.f - f2;
        const float* tb = tstat + (size_t)l * (1u << 19) * 4u;
        unsigned h1a = u1 * 2654435761u;
        unsigned h1b = (u1 + 1u) * 2654435761u;
        unsigned h2a = u2 * 805459861u;
        unsigned h2b = (u2 + 1u) * 805459861u;
        float ax = 0.f, ay = 0.f, az = 0.f, aw = 0.f;
#pragma unroll
        for (int c = 0; c < 8; ++c) {
            unsigned hh = (u0 + (c & 1)) ^ ((c & 2) ? h1b : h1a) ^ ((c & 4) ? h2b : h2a);
            unsigned idx = hh & ((1u << 19) - 1u);
            float4 v = *reinterpret_cast<const float4*>(tb + (size_t)idx * 4u);
            float w = ((c & 1) ? f0 : g0) * ((c & 2) ? f1 : g1) * ((c & 4) ? f2 : g2);
            ax += w * v.x; ay += w * v.y; az += w * v.z; aw += w * v.w;
        }
        *reinterpret_cast<float4*>(outs + (size_t)n * 32u + l * 4u) =
            make_float4(ax, ay, az, aw);
    } else {
        // ---- dynamic tri-plane, one (plane, level) ----
        unsigned dt = task - 8u;
        unsigned pl = dt >> 3, l = dt & 7u;
        float t = tptr[0];
        float idxf = t * 7.0f;               // t * (TIME_RES - 1)
        float flq = floorf(idxf);
        int i1 = (int)flq;
        int i2 = (int)ceilf(idxf);
        float w2 = idxf - flq, w1 = 1.0f - w2;

        // Lagrange coefficients at Tn = {0, 1/3, 2/3, 1}
        const float T1 = 1.f / 3.f, T2 = 2.f / 3.f;
        float a0 = t, a1 = t - T1, a2 = t - T2, a3 = t - 1.f;
        float c0 = (a1 / (0.f - T1)) * (a2 / (0.f - T2)) * (a3 / (0.f - 1.f));
        float c1 = (a0 / (T1 - 0.f)) * (a2 / (T1 - T2)) * (a3 / (T1 - 1.f));
        float c2 = (a0 / (T2 - 0.f)) * (a1 / (T2 - T1)) * (a3 / (T2 - 1.f));
        float c3 = (a0 / (1.f - 0.f)) * (a1 / (1.f - T1)) * (a2 / (1.f - T2));

        const float* tbl; unsigned Tsz; float pa, pb;
        if (pl == 0u)      { tbl = txy; Tsz = 1u << 15; pa = x0; pb = x1; }
        else if (pl == 1u) { tbl = txz; Tsz = 1u << 13; pa = x0; pb = x2; }
        else               { tbl = tyz; Tsz = 1u << 13; pa = x1; pb = x2; }
        const float* t1 = tbl + ((size_t)i1 * NLEV + l) * (size_t)Tsz * 4u;
        const float* t2 = tbl + ((size_t)i2 * NLEV + l) * (size_t)Tsz * 4u;

        float s = sc.s[l];
        float posa = pa * s + 0.5f, posb = pb * s + 0.5f;
        float fa = floorf(posa), fb = floorf(posb);
        float fra = posa - fa, frb = posb - fb;
        unsigned ua = (unsigned)fa, ub = (unsigned)fb;
        unsigned mask = Tsz - 1u;
        unsigned hb0 = ub * 2654435761u, hb1 = (ub + 1u) * 2654435761u;
        float A0 = 0.f, A1 = 0.f, A2 = 0.f, A3 = 0.f;
#pragma unroll
        for (int c = 0; c < 4; ++c) {
            unsigned idx = ((ua + (c & 1)) ^ ((c & 2) ? hb1 : hb0)) & mask;
            float4 v1 = *reinterpret_cast<const float4*>(t1 + (size_t)idx * 4u);
            float4 v2 = *reinterpret_cast<const float4*>(t2 + (size_t)idx * 4u);
            float w = ((c & 1) ? fra : 1.f - fra) * ((c & 2) ? frb : 1.f - frb);
            A0 += w * (w1 * v1.x + w2 * v2.x);
            A1 += w * (w1 * v1.y + w2 * v2.y);
            A2 += w * (w1 * v1.z + w2 * v2.z);
            A3 += w * (w1 * v1.w + w2 * v2.w);
        }
        outd[(size_t)n * 24u + dt] = c0 * A0 + c1 * A1 + c2 * A2 + c3 * A3;
    }
}

extern "C" void kernel_launch(void* const* d_in, const int* in_sizes, int n_in,
                              void* d_out, int out_size, void* d_ws, size_t ws_size,
                              hipStream_t stream) {
    const float* x     = (const float*)d_in[0];
    const float* tptr  = (const float*)d_in[1];
    const float* tstat = (const float*)d_in[2];
    const float* txy   = (const float*)d_in[3];
    const float* txz   = (const float*)d_in[4];
    const float* tyz   = (const float*)d_in[5];
    int N = in_sizes[0] / 3;
    float* outs = (float*)d_out;
    float* outd = outs + (size_t)N * 32u;

    Scales sc;
    const double pls = 6.0 / 7.0;  // log2(32768/512) / (8-1)
    for (int l = 0; l < NLEV; ++l)
        sc.s[l] = (float)(exp2((double)l * pls) * 512.0 - 1.0);

    long long total = (long long)N * 32ll;
    dim3 block(256);
    dim3 grid((unsigned)((total + 255) / 256));
    hipLaunchKernelGGL(hg4d_split_kernel, grid, block, 0, stream,
                       x, tptr, tstat, txy, txz, tyz, outs, outd, N, sc);
}